// Round 2
// 289.631 us; speedup vs baseline: 1.0253x; 1.0253x over previous
//
#include <hip/hip_runtime.h>
#include <hip/hip_bf16.h>

#define DD 128
#define TM 64
#define LD 136        // padded LDS row stride (bf16 elems)
#define SB 128        // scan blocks
#define GRID_MLP 1024 // 4 blocks/CU persistent

typedef short bf16x8 __attribute__((ext_vector_type(8)));
typedef float f32x4  __attribute__((ext_vector_type(4)));

__device__ __forceinline__ unsigned short f2bf(float f) {
  unsigned int u = __float_as_uint(f);
  u += 0x7FFFu + ((u >> 16) & 1u);   // RNE
  return (unsigned short)(u >> 16);
}
__device__ __forceinline__ unsigned int pack2(float lo, float hi) {
  return (unsigned int)f2bf(lo) | ((unsigned int)f2bf(hi) << 16);
}
__device__ __forceinline__ float bf2f(unsigned short u) {
  union { unsigned int i; float f; } x; x.i = ((unsigned int)u) << 16; return x.f;
}

// One-time fp32 -> bf16 weight conversion (64 KB total, L2-resident afterwards)
__global__ __launch_bounds__(256) void k_prep(const float* __restrict__ w1,
                                              const float* __restrict__ w2,
                                              unsigned short* __restrict__ wbf1,
                                              unsigned short* __restrict__ wbf2) {
  int i = blockIdx.x * 256 + threadIdx.x;
  if (i < DD * DD) {
    wbf1[i] = f2bf(w1[i]);
    wbf2[i] = f2bf(w2[i]);
  }
}

// cnt[dst]++ per edge (int atomics, L2-resident)
__global__ __launch_bounds__(256) void k_hist(const int* __restrict__ ei, int* __restrict__ cnt,
                                              int ne) {
  int e = blockIdx.x * 256 + threadIdx.x;
  if (e < ne) atomicAdd(&cnt[ei[ne + e]], 1);
}

// ---- 3-stage parallel exclusive scan of cnt[0..n) -> ofs[0..n], cur = ofs ----
__global__ __launch_bounds__(256) void k_scan1(const int* __restrict__ cnt,
                                               int* __restrict__ bsum, int n) {
  __shared__ int red[256];
  int b = blockIdx.x, t = threadIdx.x;
  int chunk = (n + SB - 1) / SB;
  int lo = b * chunk, hi = min(n, lo + chunk);
  int s = 0;
  for (int i = lo + t; i < hi; i += 256) s += cnt[i];
  red[t] = s;
  __syncthreads();
  for (int off = 128; off; off >>= 1) {
    if (t < off) red[t] += red[t + off];
    __syncthreads();
  }
  if (t == 0) bsum[b] = red[0];
}

__global__ __launch_bounds__(SB) void k_scan2(const int* __restrict__ bsum,
                                              int* __restrict__ bofs,
                                              int* __restrict__ ofs, int n) {
  __shared__ int tmp[SB];
  int t = threadIdx.x;
  int mine = bsum[t];
  tmp[t] = mine;
  __syncthreads();
  for (int off = 1; off < SB; off <<= 1) {
    int v = (t >= off) ? tmp[t - off] : 0;
    __syncthreads();
    tmp[t] += v;
    __syncthreads();
  }
  bofs[t] = tmp[t] - mine;
  if (t == SB - 1) ofs[n] = tmp[t];
}

__global__ __launch_bounds__(256) void k_scan3(const int* __restrict__ cnt,
                                               const int* __restrict__ bofs,
                                               int* __restrict__ ofs, int* __restrict__ cur,
                                               int n) {
  __shared__ int red[256];
  int b = blockIdx.x, t = threadIdx.x;
  int chunk  = (n + SB - 1) / SB;
  int tchunk = (chunk + 255) / 256;
  int blo = b * chunk, bhi = min(n, blo + chunk);
  int lo = blo + t * tchunk, hi = min(bhi, lo + tchunk);
  int s = 0;
  for (int i = lo; i < hi; ++i) s += cnt[i];
  int mine = s;
  red[t] = s;
  __syncthreads();
  for (int off = 1; off < 256; off <<= 1) {
    int v = (t >= off) ? red[t - off] : 0;
    __syncthreads();
    red[t] += v;
    __syncthreads();
  }
  int run = bofs[b] + red[t] - mine;
  for (int i = lo; i < hi; ++i) {
    int c = cnt[i];
    ofs[i] = run; cur[i] = run;
    run += c;
  }
}

// csr[pos] = src, pos = cur[dst]++
__global__ __launch_bounds__(256) void k_fill(const int* __restrict__ ei, int* __restrict__ cur,
                                              int* __restrict__ csr, int ne) {
  int e = blockIdx.x * 256 + threadIdx.x;
  if (e >= ne) return;
  int pos = atomicAdd(&cur[ei[ne + e]], 1);
  csr[pos] = ei[e];
}

// Dedicated high-occupancy gather: h = feat[row] + sum(neighbors), fp32 accum,
// RNE-pack to bf16 into agg (== hbuf). No LDS, low VGPR -> max waves/CU for
// latency hiding. Dual accumulator chains (2-way unroll) double load MLP.
__global__ __launch_bounds__(256) void k_agg(
    const float* __restrict__ feat, const int* __restrict__ ofs, const int* __restrict__ csr,
    unsigned short* __restrict__ agg, int nrows)
{
  int t = blockIdx.x * 256 + threadIdx.x;   // 16 threads per row, 8 cols each
  int row = t >> 4;
  if (row >= nrows) return;
  int c = (t & 15) * 8;
  const float* fr = feat + (long long)row * DD + c;
  float4 a0 = *reinterpret_cast<const float4*>(fr);
  float4 b0 = *reinterpret_cast<const float4*>(fr + 4);
  float4 a1 = make_float4(0.f, 0.f, 0.f, 0.f);
  float4 b1 = make_float4(0.f, 0.f, 0.f, 0.f);
  int o0 = ofs[row], o1 = ofs[row + 1];
  int j = o0;
  for (; j + 2 <= o1; j += 2) {
    const float* f0 = feat + (long long)csr[j]     * DD + c;
    const float* f1 = feat + (long long)csr[j + 1] * DD + c;
    float4 x0 = *reinterpret_cast<const float4*>(f0);
    float4 y0 = *reinterpret_cast<const float4*>(f0 + 4);
    float4 x1 = *reinterpret_cast<const float4*>(f1);
    float4 y1 = *reinterpret_cast<const float4*>(f1 + 4);
    a0.x += x0.x; a0.y += x0.y; a0.z += x0.z; a0.w += x0.w;
    b0.x += y0.x; b0.y += y0.y; b0.z += y0.z; b0.w += y0.w;
    a1.x += x1.x; a1.y += x1.y; a1.z += x1.z; a1.w += x1.w;
    b1.x += y1.x; b1.y += y1.y; b1.z += y1.z; b1.w += y1.w;
  }
  if (j < o1) {
    const float* f0 = feat + (long long)csr[j] * DD + c;
    float4 x0 = *reinterpret_cast<const float4*>(f0);
    float4 y0 = *reinterpret_cast<const float4*>(f0 + 4);
    a0.x += x0.x; a0.y += x0.y; a0.z += x0.z; a0.w += x0.w;
    b0.x += y0.x; b0.y += y0.y; b0.z += y0.z; b0.w += y0.w;
  }
  a0.x += a1.x; a0.y += a1.y; a0.z += a1.z; a0.w += a1.w;
  b0.x += b1.x; b0.y += b1.y; b0.z += b1.z; b0.w += b1.w;
  uint4 u;
  u.x = pack2(a0.x, a0.y); u.y = pack2(a0.z, a0.w);
  u.z = pack2(b0.x, b0.y); u.w = pack2(b0.z, b0.w);
  *reinterpret_cast<uint4*>(agg + (long long)row * DD + c) = u;
}

// Persistent fused MLP: per 64-row tile — stream bf16 agg tile from hb,
// 2-layer MLP via bf16 MFMA, epilogue writes MLP output back IN-PLACE to the
// same hb rows (tile reads complete before writes; tiles partition rows).
// NOTE: hb is read AND written (no __restrict__ — same buffer).
__global__ __launch_bounds__(256) void k_mlp(
    unsigned short* hb,
    const unsigned short* __restrict__ wbf1, const float* __restrict__ b1,
    const unsigned short* __restrict__ wbf2, const float* __restrict__ b2,
    float* __restrict__ stats, int nrows, int ntiles)
{
  __shared__ unsigned short ldsH[TM * LD];
  __shared__ unsigned short ldsH2[TM * LD];
  const int tid  = threadIdx.x;
  const int wave = tid >> 6, lane = tid & 63;
  const int q = lane >> 4, l16 = lane & 15;
  const int col0 = wave * 32;

  // Weight fragments as 16B vector loads from L2-resident bf16 arrays.
  bf16x8 bw1[2][4], bw2[2][4];
  float bias1[2], bias2[2];
  for (int n = 0; n < 2; ++n) {
    int jc = col0 + n * 16 + l16;
    bias1[n] = b1[jc];
    bias2[n] = b2[jc];
    for (int kk = 0; kk < 4; ++kk) {
      bw1[n][kk] = *reinterpret_cast<const bf16x8*>(wbf1 + jc * DD + kk * 32 + q * 8);
      bw2[n][kk] = *reinterpret_cast<const bf16x8*>(wbf2 + jc * DD + kk * 32 + q * 8);
    }
  }

  for (int tile = blockIdx.x; tile < ntiles; tile += GRID_MLP) {
    const int row0 = tile * TM;

    // Stage: coalesced bf16 tile load from hb -> padded LDS.
    for (int it = 0; it < 4; ++it) {
      int idx = it * 2048 + tid * 8;
      int r = idx >> 7, c = idx & 127;
      int row = row0 + r;
      uint4 u = make_uint4(0u, 0u, 0u, 0u);
      if (row < nrows)
        u = *reinterpret_cast<const uint4*>(hb + (long long)row * DD + c);
      *reinterpret_cast<uint4*>(&ldsH[r * LD + c]) = u;
    }
    __syncthreads();

    f32x4 acc[4][2];
    const f32x4 zero = {0.f, 0.f, 0.f, 0.f};
    for (int m = 0; m < 4; ++m) for (int n = 0; n < 2; ++n) acc[m][n] = zero;

    // GEMM1 (A: m=lane&15, k=quad*8+j)
    for (int kk = 0; kk < 4; ++kk) {
      bf16x8 aF[4];
      for (int m = 0; m < 4; ++m)
        aF[m] = *reinterpret_cast<const bf16x8*>(&ldsH[(m * 16 + l16) * LD + kk * 32 + q * 8]);
      for (int m = 0; m < 4; ++m)
        for (int n = 0; n < 2; ++n)
          acc[m][n] = __builtin_amdgcn_mfma_f32_16x16x32_bf16(aF[m], bw1[n][kk], acc[m][n], 0, 0, 0);
    }

    // h2 = relu(acc + b1) -> LDS (C/D: col=lane&15, row=quad*4+reg)
    for (int m = 0; m < 4; ++m)
      for (int n = 0; n < 2; ++n)
        for (int r = 0; r < 4; ++r) {
          float v = fmaxf(acc[m][n][r] + bias1[n], 0.f);
          ldsH2[(m * 16 + q * 4 + r) * LD + (col0 + n * 16 + l16)] = f2bf(v);
        }
    __syncthreads();

    for (int m = 0; m < 4; ++m) for (int n = 0; n < 2; ++n) acc[m][n] = zero;

    // GEMM2
    for (int kk = 0; kk < 4; ++kk) {
      bf16x8 aF[4];
      for (int m = 0; m < 4; ++m)
        aF[m] = *reinterpret_cast<const bf16x8*>(&ldsH2[(m * 16 + l16) * LD + kk * 32 + q * 8]);
      for (int m = 0; m < 4; ++m)
        for (int n = 0; n < 2; ++n)
          acc[m][n] = __builtin_amdgcn_mfma_f32_16x16x32_bf16(aF[m], bw2[n][kk], acc[m][n], 0, 0, 0);
    }

    // Epilogue: relu+bias, BN stats from fp32, pack bf16 into ldsH (reuse).
    float s[2] = {0.f, 0.f}, s2[2] = {0.f, 0.f};
    for (int m = 0; m < 4; ++m)
      for (int n = 0; n < 2; ++n) {
        int col = col0 + n * 16 + l16;
        for (int r = 0; r < 4; ++r) {
          int rl = m * 16 + q * 4 + r;
          float v = fmaxf(acc[m][n][r] + bias2[n], 0.f);
          ldsH[rl * LD + col] = f2bf(v);
          if (row0 + rl < nrows) { s[n] += v; s2[n] += v * v; }
        }
      }
    for (int off = 16; off < 64; off <<= 1)
      for (int n = 0; n < 2; ++n) {
        s[n]  += __shfl_xor(s[n], off);
        s2[n] += __shfl_xor(s2[n], off);
      }
    if (q == 0)
      for (int n = 0; n < 2; ++n) {
        int col = col0 + n * 16 + l16;
        atomicAdd(&stats[col],       s[n]);
        atomicAdd(&stats[128 + col], s2[n]);
      }
    __syncthreads();

    // Coalesced bf16 store of the tile back to hb (in-place over agg rows).
    for (int it = 0; it < 4; ++it) {
      int idx = it * 2048 + tid * 8;
      int r = idx >> 7, c = idx & 127;
      int row = row0 + r;
      if (row < nrows)
        *reinterpret_cast<uint4*>(hb + (long long)row * DD + c) =
            *reinterpret_cast<const uint4*>(&ldsH[r * LD + c]);
    }
    __syncthreads();  // protect ldsH before next tile's staging
  }
}

// stats -> scale/shift
__global__ __launch_bounds__(128) void k_stats(const float* __restrict__ stats,
                                               const float* __restrict__ gamma,
                                               const float* __restrict__ beta,
                                               float* __restrict__ scsh, int nrows) {
  int t = threadIdx.x;
  float mean = stats[t] / (float)nrows;
  float var  = fmaxf(stats[128 + t] / (float)nrows - mean * mean, 0.f);
  float inv  = rsqrtf(var + 1e-5f);
  float sc   = gamma[t] * inv;
  scsh[t]       = sc;
  scsh[128 + t] = beta[t] - mean * sc;
}

// BN apply: read bf16 hbuf (L3-warm), write fp32 out. One thread per 8 elems.
__global__ __launch_bounds__(256) void k_bn(const unsigned short* __restrict__ hbuf,
                                            float* __restrict__ out,
                                            const float* __restrict__ scsh,
                                            long long total8) {
  long long t = (long long)blockIdx.x * 256 + threadIdx.x;
  if (t >= total8) return;
  int c0 = (int)((t * 8) & 127);
  float4 sa = *reinterpret_cast<const float4*>(scsh + c0);
  float4 sb = *reinterpret_cast<const float4*>(scsh + c0 + 4);
  float4 ha = *reinterpret_cast<const float4*>(scsh + 128 + c0);
  float4 hb = *reinterpret_cast<const float4*>(scsh + 132 + c0);
  uint4 u = *reinterpret_cast<const uint4*>(hbuf + t * 8);
  float4 a, b;
  a.x = bf2f((unsigned short)(u.x & 0xFFFF)) * sa.x + ha.x;
  a.y = bf2f((unsigned short)(u.x >> 16))    * sa.y + ha.y;
  a.z = bf2f((unsigned short)(u.y & 0xFFFF)) * sa.z + ha.z;
  a.w = bf2f((unsigned short)(u.y >> 16))    * sa.w + ha.w;
  b.x = bf2f((unsigned short)(u.z & 0xFFFF)) * sb.x + hb.x;
  b.y = bf2f((unsigned short)(u.z >> 16))    * sb.y + hb.y;
  b.z = bf2f((unsigned short)(u.w & 0xFFFF)) * sb.z + hb.z;
  b.w = bf2f((unsigned short)(u.w >> 16))    * sb.w + hb.w;
  float* of = out + t * 8;
  *reinterpret_cast<float4*>(of)     = a;
  *reinterpret_cast<float4*>(of + 4) = b;
}

extern "C" void kernel_launch(void* const* d_in, const int* in_sizes, int n_in,
                              void* d_out, int out_size, void* d_ws, size_t ws_size,
                              hipStream_t stream) {
  const float* feat  = (const float*)d_in[0];
  const int*   eidx  = (const int*)d_in[1];
  const float* w1    = (const float*)d_in[2];
  const float* b1    = (const float*)d_in[3];
  const float* w2    = (const float*)d_in[4];
  const float* b2    = (const float*)d_in[5];
  const float* gamma = (const float*)d_in[6];
  const float* beta  = (const float*)d_in[7];
  float* out = (float*)d_out;

  const int nrows  = in_sizes[0] / DD;       // 100000
  const int ne     = in_sizes[1] / 2;        // 400000
  const int ntiles = (nrows + TM - 1) / TM;  // 1563

  // ws layout (4B words), hbuf last (16B-aligned by construction):
  int* base = (int*)d_ws;
  unsigned short* wbf1 = (unsigned short*)base;            // 8192 words
  unsigned short* wbf2 = (unsigned short*)(base + 8192);   // 8192 words
  float* scsh  = (float*)(base + 16384);                   // 256
  int*   ofs   = base + 16384 + 256;                       // nrows+1
  int*   cur   = ofs + (nrows + 1);
  int*   csr   = cur + nrows;
  int*   bsum  = csr + ne;
  int*   bofs  = bsum + SB;
  float* stats = (float*)(bofs + SB);                      // 256
  int*   cnt   = (int*)(stats + 256);                      // nrows
  long long w_off = (long long)(cnt + nrows - base);
  w_off = (w_off + 3) & ~3LL;                              // 16B align
  unsigned short* hbuf = (unsigned short*)(base + w_off);  // nrows*DD bf16 (25.6 MB)

  hipMemsetAsync(stats, 0, (256 + (size_t)nrows) * sizeof(float), stream);

  const long long total8 = (long long)nrows * DD / 8;      // 1.6M
  const int agg_blocks = (nrows * 16 + 255) / 256;         // 6250

  k_prep <<<(DD * DD + 255) / 256,        256, 0, stream>>>(w1, w2, wbf1, wbf2);
  k_hist <<<(ne + 255) / 256,             256, 0, stream>>>(eidx, cnt, ne);
  k_scan1<<<SB,                           256, 0, stream>>>(cnt, bsum, nrows);
  k_scan2<<<1,                             SB, 0, stream>>>(bsum, bofs, ofs, nrows);
  k_scan3<<<SB,                           256, 0, stream>>>(cnt, bofs, ofs, cur, nrows);
  k_fill <<<(ne + 255) / 256,             256, 0, stream>>>(eidx, cur, csr, ne);
  k_agg  <<<agg_blocks,                   256, 0, stream>>>(feat, ofs, csr, hbuf, nrows);
  k_mlp  <<<GRID_MLP,                     256, 0, stream>>>(hbuf, wbf1, b1, wbf2, b2,
                                                            stats, nrows, ntiles);
  k_stats<<<1,                            128, 0, stream>>>(stats, gamma, beta, scsh, nrows);
  k_bn   <<<(int)((total8 + 255) / 256),  256, 0, stream>>>(hbuf, out, scsh, total8);
}

// Round 3
// 251.439 us; speedup vs baseline: 1.1810x; 1.1519x over previous
//
#include <hip/hip_runtime.h>
#include <hip/hip_bf16.h>

#define DD 128
#define TM 64
#define LD 136        // padded LDS row stride (bf16 elems)
#define SB 128        // scan blocks
#define GRID_MLP 1024 // 4 blocks/CU persistent

typedef short bf16x8 __attribute__((ext_vector_type(8)));
typedef float f32x4  __attribute__((ext_vector_type(4)));

__device__ __forceinline__ unsigned short f2bf(float f) {
  unsigned int u = __float_as_uint(f);
  u += 0x7FFFu + ((u >> 16) & 1u);   // RNE
  return (unsigned short)(u >> 16);
}
__device__ __forceinline__ unsigned int pack2(float lo, float hi) {
  return (unsigned int)f2bf(lo) | ((unsigned int)f2bf(hi) << 16);
}
__device__ __forceinline__ float bf2f(unsigned short u) {
  union { unsigned int i; float f; } x; x.i = ((unsigned int)u) << 16; return x.f;
}

// One-time fp32 -> bf16 weight conversion (64 KB total, L2-resident afterwards)
__global__ __launch_bounds__(256) void k_prep(const float* __restrict__ w1,
                                              const float* __restrict__ w2,
                                              unsigned short* __restrict__ wbf1,
                                              unsigned short* __restrict__ wbf2) {
  int i = blockIdx.x * 256 + threadIdx.x;
  if (i < DD * DD) {
    wbf1[i] = f2bf(w1[i]);
    wbf2[i] = f2bf(w2[i]);
  }
}

// cnt[dst]++ per edge (int atomics, L2-resident)
__global__ __launch_bounds__(256) void k_hist(const int* __restrict__ ei, int* __restrict__ cnt,
                                              int ne) {
  int e = blockIdx.x * 256 + threadIdx.x;
  if (e < ne) atomicAdd(&cnt[ei[ne + e]], 1);
}

// ---- 3-stage parallel exclusive scan of cnt[0..n) -> ofs[0..n], cur = ofs ----
__global__ __launch_bounds__(256) void k_scan1(const int* __restrict__ cnt,
                                               int* __restrict__ bsum, int n) {
  __shared__ int red[256];
  int b = blockIdx.x, t = threadIdx.x;
  int chunk = (n + SB - 1) / SB;
  int lo = b * chunk, hi = min(n, lo + chunk);
  int s = 0;
  for (int i = lo + t; i < hi; i += 256) s += cnt[i];
  red[t] = s;
  __syncthreads();
  for (int off = 128; off; off >>= 1) {
    if (t < off) red[t] += red[t + off];
    __syncthreads();
  }
  if (t == 0) bsum[b] = red[0];
}

__global__ __launch_bounds__(SB) void k_scan2(const int* __restrict__ bsum,
                                              int* __restrict__ bofs,
                                              int* __restrict__ ofs, int n) {
  __shared__ int tmp[SB];
  int t = threadIdx.x;
  int mine = bsum[t];
  tmp[t] = mine;
  __syncthreads();
  for (int off = 1; off < SB; off <<= 1) {
    int v = (t >= off) ? tmp[t - off] : 0;
    __syncthreads();
    tmp[t] += v;
    __syncthreads();
  }
  bofs[t] = tmp[t] - mine;
  if (t == SB - 1) ofs[n] = tmp[t];
}

__global__ __launch_bounds__(256) void k_scan3(const int* __restrict__ cnt,
                                               const int* __restrict__ bofs,
                                               int* __restrict__ ofs, int* __restrict__ cur,
                                               int n) {
  __shared__ int red[256];
  int b = blockIdx.x, t = threadIdx.x;
  int chunk  = (n + SB - 1) / SB;
  int tchunk = (chunk + 255) / 256;
  int blo = b * chunk, bhi = min(n, blo + chunk);
  int lo = blo + t * tchunk, hi = min(bhi, lo + tchunk);
  int s = 0;
  for (int i = lo; i < hi; ++i) s += cnt[i];
  int mine = s;
  red[t] = s;
  __syncthreads();
  for (int off = 1; off < 256; off <<= 1) {
    int v = (t >= off) ? red[t - off] : 0;
    __syncthreads();
    red[t] += v;
    __syncthreads();
  }
  int run = bofs[b] + red[t] - mine;
  for (int i = lo; i < hi; ++i) {
    int c = cnt[i];
    ofs[i] = run; cur[i] = run;
    run += c;
  }
}

// csr[pos] = src, pos = cur[dst]++
__global__ __launch_bounds__(256) void k_fill(const int* __restrict__ ei, int* __restrict__ cur,
                                              int* __restrict__ csr, int ne) {
  int e = blockIdx.x * 256 + threadIdx.x;
  if (e >= ne) return;
  int pos = atomicAdd(&cur[ei[ne + e]], 1);
  csr[pos] = ei[e];
}

// Dedicated high-occupancy gather: h = feat[row] + sum(neighbors), fp32 accum,
// RNE-pack to bf16 into agg (== hbuf). No LDS, low VGPR -> max waves/CU for
// latency hiding. Dual accumulator chains (2-way unroll) double load MLP.
__global__ __launch_bounds__(256) void k_agg(
    const float* __restrict__ feat, const int* __restrict__ ofs, const int* __restrict__ csr,
    unsigned short* __restrict__ agg, int nrows)
{
  int t = blockIdx.x * 256 + threadIdx.x;   // 16 threads per row, 8 cols each
  int row = t >> 4;
  if (row >= nrows) return;
  int c = (t & 15) * 8;
  const float* fr = feat + (long long)row * DD + c;
  float4 a0 = *reinterpret_cast<const float4*>(fr);
  float4 b0 = *reinterpret_cast<const float4*>(fr + 4);
  float4 a1 = make_float4(0.f, 0.f, 0.f, 0.f);
  float4 b1 = make_float4(0.f, 0.f, 0.f, 0.f);
  int o0 = ofs[row], o1 = ofs[row + 1];
  int j = o0;
  for (; j + 2 <= o1; j += 2) {
    const float* f0 = feat + (long long)csr[j]     * DD + c;
    const float* f1 = feat + (long long)csr[j + 1] * DD + c;
    float4 x0 = *reinterpret_cast<const float4*>(f0);
    float4 y0 = *reinterpret_cast<const float4*>(f0 + 4);
    float4 x1 = *reinterpret_cast<const float4*>(f1);
    float4 y1 = *reinterpret_cast<const float4*>(f1 + 4);
    a0.x += x0.x; a0.y += x0.y; a0.z += x0.z; a0.w += x0.w;
    b0.x += y0.x; b0.y += y0.y; b0.z += y0.z; b0.w += y0.w;
    a1.x += x1.x; a1.y += x1.y; a1.z += x1.z; a1.w += x1.w;
    b1.x += y1.x; b1.y += y1.y; b1.z += y1.z; b1.w += y1.w;
  }
  if (j < o1) {
    const float* f0 = feat + (long long)csr[j] * DD + c;
    float4 x0 = *reinterpret_cast<const float4*>(f0);
    float4 y0 = *reinterpret_cast<const float4*>(f0 + 4);
    a0.x += x0.x; a0.y += x0.y; a0.z += x0.z; a0.w += x0.w;
    b0.x += y0.x; b0.y += y0.y; b0.z += y0.z; b0.w += y0.w;
  }
  a0.x += a1.x; a0.y += a1.y; a0.z += a1.z; a0.w += a1.w;
  b0.x += b1.x; b0.y += b1.y; b0.z += b1.z; b0.w += b1.w;
  uint4 u;
  u.x = pack2(a0.x, a0.y); u.y = pack2(a0.z, a0.w);
  u.z = pack2(b0.x, b0.y); u.w = pack2(b0.z, b0.w);
  *reinterpret_cast<uint4*>(agg + (long long)row * DD + c) = u;
}

// Persistent fused MLP: per 64-row tile — stream bf16 agg tile from hb,
// 2-layer MLP via bf16 MFMA, epilogue writes MLP output back IN-PLACE to the
// same hb rows. BN stats: register-accumulated across tiles, ONE non-atomic
// store per block into partial[block][256] (no contended atomics).
__global__ __launch_bounds__(256) void k_mlp(
    unsigned short* hb,
    const unsigned short* __restrict__ wbf1, const float* __restrict__ b1,
    const unsigned short* __restrict__ wbf2, const float* __restrict__ b2,
    float* __restrict__ partial, int nrows, int ntiles)
{
  __shared__ unsigned short ldsH[TM * LD];
  __shared__ unsigned short ldsH2[TM * LD];
  const int tid  = threadIdx.x;
  const int wave = tid >> 6, lane = tid & 63;
  const int q = lane >> 4, l16 = lane & 15;
  const int col0 = wave * 32;

  // Weight fragments as 16B vector loads from L2-resident bf16 arrays.
  bf16x8 bw1[2][4], bw2[2][4];
  float bias1[2], bias2[2];
  for (int n = 0; n < 2; ++n) {
    int jc = col0 + n * 16 + l16;
    bias1[n] = b1[jc];
    bias2[n] = b2[jc];
    for (int kk = 0; kk < 4; ++kk) {
      bw1[n][kk] = *reinterpret_cast<const bf16x8*>(wbf1 + jc * DD + kk * 32 + q * 8);
      bw2[n][kk] = *reinterpret_cast<const bf16x8*>(wbf2 + jc * DD + kk * 32 + q * 8);
    }
  }

  // BN-stat accumulators, carried across all tiles of this block.
  float fs[2] = {0.f, 0.f}, fs2[2] = {0.f, 0.f};

  for (int tile = blockIdx.x; tile < ntiles; tile += GRID_MLP) {
    const int row0 = tile * TM;

    // Stage: coalesced bf16 tile load from hb -> padded LDS.
    for (int it = 0; it < 4; ++it) {
      int idx = it * 2048 + tid * 8;
      int r = idx >> 7, c = idx & 127;
      int row = row0 + r;
      uint4 u = make_uint4(0u, 0u, 0u, 0u);
      if (row < nrows)
        u = *reinterpret_cast<const uint4*>(hb + (long long)row * DD + c);
      *reinterpret_cast<uint4*>(&ldsH[r * LD + c]) = u;
    }
    __syncthreads();

    f32x4 acc[4][2];
    const f32x4 zero = {0.f, 0.f, 0.f, 0.f};
    for (int m = 0; m < 4; ++m) for (int n = 0; n < 2; ++n) acc[m][n] = zero;

    // GEMM1 (A: m=lane&15, k=quad*8+j)
    for (int kk = 0; kk < 4; ++kk) {
      bf16x8 aF[4];
      for (int m = 0; m < 4; ++m)
        aF[m] = *reinterpret_cast<const bf16x8*>(&ldsH[(m * 16 + l16) * LD + kk * 32 + q * 8]);
      for (int m = 0; m < 4; ++m)
        for (int n = 0; n < 2; ++n)
          acc[m][n] = __builtin_amdgcn_mfma_f32_16x16x32_bf16(aF[m], bw1[n][kk], acc[m][n], 0, 0, 0);
    }

    // h2 = relu(acc + b1) -> LDS (C/D: col=lane&15, row=quad*4+reg)
    for (int m = 0; m < 4; ++m)
      for (int n = 0; n < 2; ++n)
        for (int r = 0; r < 4; ++r) {
          float v = fmaxf(acc[m][n][r] + bias1[n], 0.f);
          ldsH2[(m * 16 + q * 4 + r) * LD + (col0 + n * 16 + l16)] = f2bf(v);
        }
    __syncthreads();

    for (int m = 0; m < 4; ++m) for (int n = 0; n < 2; ++n) acc[m][n] = zero;

    // GEMM2
    for (int kk = 0; kk < 4; ++kk) {
      bf16x8 aF[4];
      for (int m = 0; m < 4; ++m)
        aF[m] = *reinterpret_cast<const bf16x8*>(&ldsH2[(m * 16 + l16) * LD + kk * 32 + q * 8]);
      for (int m = 0; m < 4; ++m)
        for (int n = 0; n < 2; ++n)
          acc[m][n] = __builtin_amdgcn_mfma_f32_16x16x32_bf16(aF[m], bw2[n][kk], acc[m][n], 0, 0, 0);
    }

    // Epilogue: relu+bias, accumulate BN stats in registers, pack bf16 -> ldsH.
    for (int m = 0; m < 4; ++m)
      for (int n = 0; n < 2; ++n) {
        int col = col0 + n * 16 + l16;
        for (int r = 0; r < 4; ++r) {
          int rl = m * 16 + q * 4 + r;
          float v = fmaxf(acc[m][n][r] + bias2[n], 0.f);
          ldsH[rl * LD + col] = f2bf(v);
          if (row0 + rl < nrows) { fs[n] += v; fs2[n] += v * v; }
        }
      }
    __syncthreads();

    // Coalesced bf16 store of the tile back to hb (in-place over agg rows).
    for (int it = 0; it < 4; ++it) {
      int idx = it * 2048 + tid * 8;
      int r = idx >> 7, c = idx & 127;
      int row = row0 + r;
      if (row < nrows)
        *reinterpret_cast<uint4*>(hb + (long long)row * DD + c) =
            *reinterpret_cast<const uint4*>(&ldsH[r * LD + c]);
    }
    __syncthreads();  // protect ldsH before next tile's staging
  }

  // One shuffle-reduce + one non-atomic store per block.
  for (int off = 16; off < 64; off <<= 1)
    for (int n = 0; n < 2; ++n) {
      fs[n]  += __shfl_xor(fs[n], off);
      fs2[n] += __shfl_xor(fs2[n], off);
    }
  if (q == 0) {
    float* pb = partial + (long long)blockIdx.x * 256;
    for (int n = 0; n < 2; ++n) {
      int col = col0 + n * 16 + l16;
      pb[col]       = fs[n];
      pb[128 + col] = fs2[n];
    }
  }
}

// Reduce per-block partials -> scale/shift
__global__ __launch_bounds__(256) void k_stats(const float* __restrict__ partial,
                                               const float* __restrict__ gamma,
                                               const float* __restrict__ beta,
                                               float* __restrict__ scsh, int nrows) {
  __shared__ float red[256];
  int t = threadIdx.x;
  float s = 0.f;
  for (int b = 0; b < GRID_MLP; ++b) s += partial[(long long)b * 256 + t];
  red[t] = s;
  __syncthreads();
  if (t < 128) {
    float mean = red[t] / (float)nrows;
    float var  = fmaxf(red[128 + t] / (float)nrows - mean * mean, 0.f);
    float inv  = rsqrtf(var + 1e-5f);
    float sc   = gamma[t] * inv;
    scsh[t]       = sc;
    scsh[128 + t] = beta[t] - mean * sc;
  }
}

// BN apply: read bf16 hbuf (L3-warm), write fp32 out. One thread per 8 elems.
__global__ __launch_bounds__(256) void k_bn(const unsigned short* __restrict__ hbuf,
                                            float* __restrict__ out,
                                            const float* __restrict__ scsh,
                                            long long total8) {
  long long t = (long long)blockIdx.x * 256 + threadIdx.x;
  if (t >= total8) return;
  int c0 = (int)((t * 8) & 127);
  float4 sa = *reinterpret_cast<const float4*>(scsh + c0);
  float4 sb = *reinterpret_cast<const float4*>(scsh + c0 + 4);
  float4 ha = *reinterpret_cast<const float4*>(scsh + 128 + c0);
  float4 hb = *reinterpret_cast<const float4*>(scsh + 132 + c0);
  uint4 u = *reinterpret_cast<const uint4*>(hbuf + t * 8);
  float4 a, b;
  a.x = bf2f((unsigned short)(u.x & 0xFFFF)) * sa.x + ha.x;
  a.y = bf2f((unsigned short)(u.x >> 16))    * sa.y + ha.y;
  a.z = bf2f((unsigned short)(u.y & 0xFFFF)) * sa.z + ha.z;
  a.w = bf2f((unsigned short)(u.y >> 16))    * sa.w + ha.w;
  b.x = bf2f((unsigned short)(u.z & 0xFFFF)) * sb.x + hb.x;
  b.y = bf2f((unsigned short)(u.z >> 16))    * sb.y + hb.y;
  b.z = bf2f((unsigned short)(u.w & 0xFFFF)) * sb.z + hb.z;
  b.w = bf2f((unsigned short)(u.w >> 16))    * sb.w + hb.w;
  float* of = out + t * 8;
  *reinterpret_cast<float4*>(of)     = a;
  *reinterpret_cast<float4*>(of + 4) = b;
}

extern "C" void kernel_launch(void* const* d_in, const int* in_sizes, int n_in,
                              void* d_out, int out_size, void* d_ws, size_t ws_size,
                              hipStream_t stream) {
  const float* feat  = (const float*)d_in[0];
  const int*   eidx  = (const int*)d_in[1];
  const float* w1    = (const float*)d_in[2];
  const float* b1    = (const float*)d_in[3];
  const float* w2    = (const float*)d_in[4];
  const float* b2    = (const float*)d_in[5];
  const float* gamma = (const float*)d_in[6];
  const float* beta  = (const float*)d_in[7];
  float* out = (float*)d_out;

  const int nrows  = in_sizes[0] / DD;       // 100000
  const int ne     = in_sizes[1] / 2;        // 400000
  const int ntiles = (nrows + TM - 1) / TM;  // 1563

  // ws layout (4B words), hbuf last (16B-aligned by construction):
  int* base = (int*)d_ws;
  unsigned short* wbf1 = (unsigned short*)base;            // 8192 words
  unsigned short* wbf2 = (unsigned short*)(base + 8192);   // 8192 words
  float* scsh  = (float*)(base + 16384);                   // 256
  int*   ofs   = base + 16384 + 256;                       // nrows+1
  int*   cur   = ofs + (nrows + 1);
  int*   csr   = cur + nrows;
  int*   bsum  = csr + ne;
  int*   bofs  = bsum + SB;
  float* partial = (float*)(bofs + SB);                    // GRID_MLP*256 (1 MB)
  int*   cnt   = (int*)(partial + (size_t)GRID_MLP * 256); // nrows
  long long w_off = (long long)(cnt + nrows - base);
  w_off = (w_off + 3) & ~3LL;                              // 16B align
  unsigned short* hbuf = (unsigned short*)(base + w_off);  // nrows*DD bf16 (25.6 MB)

  hipMemsetAsync(cnt, 0, (size_t)nrows * sizeof(int), stream);

  const long long total8 = (long long)nrows * DD / 8;      // 1.6M
  const int agg_blocks = (nrows * 16 + 255) / 256;         // 6250

  k_prep <<<(DD * DD + 255) / 256,        256, 0, stream>>>(w1, w2, wbf1, wbf2);
  k_hist <<<(ne + 255) / 256,             256, 0, stream>>>(eidx, cnt, ne);
  k_scan1<<<SB,                           256, 0, stream>>>(cnt, bsum, nrows);
  k_scan2<<<1,                             SB, 0, stream>>>(bsum, bofs, ofs, nrows);
  k_scan3<<<SB,                           256, 0, stream>>>(cnt, bofs, ofs, cur, nrows);
  k_fill <<<(ne + 255) / 256,             256, 0, stream>>>(eidx, cur, csr, ne);
  k_agg  <<<agg_blocks,                   256, 0, stream>>>(feat, ofs, csr, hbuf, nrows);
  k_mlp  <<<GRID_MLP,                     256, 0, stream>>>(hbuf, wbf1, b1, wbf2, b2,
                                                            partial, nrows, ntiles);
  k_stats<<<1,                            256, 0, stream>>>(partial, gamma, beta, scsh, nrows);
  k_bn   <<<(int)((total8 + 255) / 256),  256, 0, stream>>>(hbuf, out, scsh, total8);
}